// Round 14
// baseline (61.201 us; speedup 1.0000x reference)
//
#include <hip/hip_runtime.h>
#include <hip/hip_bf16.h>

typedef float f32x16 __attribute__((ext_vector_type(16)));
typedef short short8 __attribute__((ext_vector_type(8)));

#define N_IMG 32
#define C_CH  128
#define HW    9216
#define K_CL  64
#define EPSF  1e-12f

#define BPI   16      // blocks per image (grid 512 = exactly 2/CU)
#define PPB   576     // pixels per block
#define NHALF 9       // 9 tiles of 64 pixels

// ws layout (floats)
#define WS_VLAD 0
#define WS_ASUM (N_IMG*K_CL*C_CH)              // 262144
#define WS_ZERO (WS_ASUM + N_IMG*K_CL)         // 264192 (zeroed prefix, atomic path)
#define WS_PART WS_ZERO
#define NPART   (N_IMG*BPI)                    // 512
#define WS_ASP  (WS_PART + NPART*K_CL*C_CH/2)  // part is bf16
#define WS_STORE_TOT (WS_ASP + NPART*K_CL)

__device__ __forceinline__ unsigned short bfb(float f) {
    __hip_bfloat16 h = __float2bfloat16(f);   // RNE
    return *reinterpret_cast<unsigned short*>(&h);
}
__device__ __forceinline__ float b2f(unsigned short s) {
    return __uint_as_float(((unsigned)s) << 16);
}

typedef const __attribute__((address_space(1))) void gv_t;
typedef __attribute__((address_space(3))) void lv_t;
__device__ __forceinline__ void gload16(const void* g, void* l) {
    __builtin_amdgcn_global_load_lds((gv_t*)g, (lv_t*)l, 16, 0, 0);
}
#define SBAR()  __builtin_amdgcn_s_barrier()
#define SCHED() __builtin_amdgcn_sched_barrier(0)
#define WAITL() do { asm volatile("s_waitcnt lgkmcnt(0)" ::: "memory"); SCHED(); } while (0)
#define WAITV() do { asm volatile("s_waitcnt vmcnt(0)" ::: "memory"); SCHED(); } while (0)

__global__ void k_zero(float* __restrict__ p, int cnt) {
    int i = blockIdx.x * blockDim.x + threadIdx.x;
    if (i < cnt) p[i] = 0.f;
}

__global__ __launch_bounds__(256, 2) void k_fused11(
    const float* __restrict__ x, const float* __restrict__ conv_w,
    float* __restrict__ vlad, float* __restrict__ asum,
    unsigned short* __restrict__ part, float* __restrict__ aspart, int use_part)
{
    // cw: pitch 256B swz ^((k&7)<<4). s: pitch 128B swz ^((k&7)<<4).
    // xs: fp32 [128c][64p], SOURCE-swizzled 16B chunks: slot(row,Q) holds px 4*(Q^(row&7))
    __shared__ __align__(16) char cw_lds[64 * 256];    // 16KB
    __shared__ __align__(16) char xs_lds[128 * 256];   // 32KB (wave-private row bands)
    __shared__ __align__(16) char s_lds [64 * 128];    // raw e bf16 [64k][64p] 8KB
    __shared__ __align__(16) float smpart[2][64];
    __shared__ __align__(16) float invt[64];
    __shared__ __align__(16) float sc2t[64];

    const int t  = threadIdx.x;
    const int w  = t >> 6;          // wave 0..3
    const int l  = t & 63;
    const int lp = l & 31;
    const int h  = l >> 5;
    const int n    = blockIdx.x / BPI;
    const int pblk = (blockIdx.x % BPI) * PPB;

    const int kh  = w >> 1;                 // logits k-half
    const int p   = ((w & 1) << 5) + lp;    // pixel 0..63
    const int p2  = p << 1;
    const int ks  = t >> 2;                 // asum k row
    const int st4 = t & 3;                  // asum strip
    const float* xbase = x + (size_t)n * C_CH * HW;

    // LDS bases
    const int swzL = (lp & 7) << 4;
    const int hx   = h << 4;
    const int bCW  = (((kh << 5) + lp) << 8) | (hx ^ swzL);   // logits A (^ s<<5)
    const int cB   = (w << 5) + lp;                            // VLAD c-column
    const int swzC = (cB & 7) << 4;
    const int bS0  = (lp << 7)        | (hx ^ swzL);           // s_lds rows lp
    const int bS1  = ((32 + lp) << 7) | (hx ^ swzL);           // s_lds rows 32+lp
    int baseS[4];
    #pragma unroll
    for (int j = 0; j < 4; ++j)
        baseS[j] = (kh << 12) + (h << 9) + (p2 ^ (j << 4) ^ (h << 6));

    // DMA: wave w covers c-rows 32w..32w+31; source pre-swizzled so reads can XOR
    #define ISSUE_DMA(OFF) do { \
        _Pragma("unroll") \
        for (int j_ = 0; j_ < 8; ++j_) { \
            const int rloc = (l >> 4) + 4 * j_; \
            const int pxs  = ((l & 15) ^ (rloc & 7)) << 2; \
            gload16(xbase + pblk + (OFF) + (size_t)((w << 5) + rloc) * HW + pxs, \
                    xs_lds + ((((w << 5) + 4 * j_)) << 8)); \
        } } while (0)

    // ---- prologue: DMA tile 0 ASAP, then stage conv_w ----
    ISSUE_DMA(0);
    SCHED();
    #pragma unroll
    for (int r = 0; r < 16; ++r) {
        int e  = t + 256 * r;
        int k  = e >> 6;
        int c2 = (e & 63) << 1;
        unsigned pa = (unsigned)bfb(conv_w[k * C_CH + c2]) |
                      ((unsigned)bfb(conv_w[k * C_CH + c2 + 1]) << 16);
        int addr = (((k << 8) | (c2 << 1)) ^ ((k & 7) << 4));
        *reinterpret_cast<unsigned*>(cw_lds + addr) = pa;
    }

    f32x16 va0, va1;
    #pragma unroll
    for (int r = 0; r < 16; ++r) { va0[r] = 0.f; va1[r] = 0.f; }
    float asum_acc = 0.f;

    WAITL(); SBAR();   // cw ready (DMA still in flight)

    for (int it = 0; it < NHALF; ++it) {
        if (it) { WAITL(); SBAR(); }   // C: prev iter's s_lds/invt/sc2t readers done

        // ---- front-end: direct per-lane global loads (coalesced; L2-warmed by DMA) ----
        const float* xp = xbase + pblk + it * 64 + p;
        float ss = 0.f;
        short8 xb[8];
        #pragma unroll
        for (int s = 0; s < 8; ++s) {
            float xv[8];
            #pragma unroll
            for (int i = 0; i < 8; ++i)
                xv[i] = xp[(size_t)(16 * s + 8 * h + i) * HW];
            #pragma unroll
            for (int i = 0; i < 8; ++i) ss += xv[i] * xv[i];
            #pragma unroll
            for (int i = 0; i < 8; ++i) xb[s][i] = (short)bfb(xv[i]);
        }
        ss += __shfl_xor(ss, 32);
        const float scn = 1.f / fmaxf(sqrtf(ss), EPSF);

        // ---- logits MFMA: [32k(kh) x 32p], K=128 ----
        f32x16 d;
        #pragma unroll
        for (int r = 0; r < 16; ++r) d[r] = 0.f;
        #pragma unroll
        for (int s8 = 0; s8 < 8; ++s8) {
            short8 a = *reinterpret_cast<const short8*>(cw_lds + (bCW ^ (s8 << 5)));
            d = __builtin_amdgcn_mfma_f32_32x32x16_bf16(a, xb[s8], d, 0, 0, 0);
        }

        // ---- e = exp(d*scn) (bounded: |logit·scn| <~ 1.4); raw-e stores; denom ----
        float sm = 0.f;
        #pragma unroll
        for (int r = 0; r < 16; ++r) {
            float e = __expf(d[r] * scn);
            sm += e;
            const int imm = ((r & 3) << 7) + ((r >> 2) << 10);
            *reinterpret_cast<short*>(s_lds + (baseS[r & 3] + imm)) = (short)bfb(e);
        }
        sm += __shfl_xor(sm, 32);
        if (h == 0) smpart[kh][p] = sm;
        WAITL(); SBAR();               // A: smpart + e-stores visible

        const float inv = 1.f / (smpart[0][p] + smpart[1][p]);
        if (kh == 0 && h == 0) { invt[p] = inv; sc2t[p] = scn * inv; }
        WAITL(); SBAR();               // B: invt/sc2t visible

        WAITV();                       // xs[it] landed (wave-local DMA)

        // ---- VLAD MFMA: A = raw e, B = xs fp32 * sc2[pix] converted on the fly ----
        #pragma unroll
        for (int sp = 0; sp < 4; ++sp) {
            const int boffp = (sp << 6) + (h << 5);            // pixel byte offset
            const int a0 = (cB << 8) + (boffp ^ swzC);
            float4 f0 = *reinterpret_cast<const float4*>(xs_lds + a0);
            float4 f1 = *reinterpret_cast<const float4*>(xs_lds + (a0 ^ 16));
            const int pix0 = (sp << 4) + (h << 3);
            float4 s2a = *reinterpret_cast<const float4*>(sc2t + pix0);
            float4 s2b = *reinterpret_cast<const float4*>(sc2t + pix0 + 4);
            short8 bf;
            bf[0] = (short)bfb(f0.x * s2a.x); bf[1] = (short)bfb(f0.y * s2a.y);
            bf[2] = (short)bfb(f0.z * s2a.z); bf[3] = (short)bfb(f0.w * s2a.w);
            bf[4] = (short)bfb(f1.x * s2b.x); bf[5] = (short)bfb(f1.y * s2b.y);
            bf[6] = (short)bfb(f1.z * s2b.z); bf[7] = (short)bfb(f1.w * s2b.w);
            short8 s0 = *reinterpret_cast<const short8*>(s_lds + (bS0 ^ (sp << 5)));
            short8 s1 = *reinterpret_cast<const short8*>(s_lds + (bS1 ^ (sp << 5)));
            va0 = __builtin_amdgcn_mfma_f32_32x32x16_bf16(s0, bf, va0, 0, 0, 0);
            va1 = __builtin_amdgcn_mfma_f32_32x32x16_bf16(s1, bf, va1, 0, 0, 0);
        }

        WAITL();                       // own xs reads retired before overwrite
        if (it + 1 < NHALF) ISSUE_DMA((it + 1) * 64);
        SCHED();

        // ---- asum strips: soft = raw e * invt[p] ----
        {
            const int rowb = ks << 7;
            const int swz  = (ks & 7) << 4;
            const float* ivp = invt + (st4 << 4);
            float a = 0.f;
            #pragma unroll
            for (int g = 0; g < 2; ++g) {
                int off = (st4 << 5) | (g << 4);
                short8 u = *reinterpret_cast<const short8*>(s_lds + (rowb | (off ^ swz)));
                float4 ia = *reinterpret_cast<const float4*>(ivp + g * 8);
                float4 ib = *reinterpret_cast<const float4*>(ivp + g * 8 + 4);
                a += b2f((unsigned short)u[0]) * ia.x + b2f((unsigned short)u[1]) * ia.y +
                     b2f((unsigned short)u[2]) * ia.z + b2f((unsigned short)u[3]) * ia.w;
                a += b2f((unsigned short)u[4]) * ib.x + b2f((unsigned short)u[5]) * ib.y +
                     b2f((unsigned short)u[6]) * ib.z + b2f((unsigned short)u[7]) * ib.w;
            }
            asum_acc += a;
        }
    }

    // ---- flush partials ----
    if (use_part) {
        unsigned short* pb_ = part + (size_t)blockIdx.x * (K_CL * C_CH) + cB;
        #pragma unroll
        for (int r = 0; r < 16; ++r) {
            const int kr = (r & 3) + 8 * (r >> 2) + 4 * h;
            pb_[(kr)      * C_CH] = bfb(va0[r]);
            pb_[(32 + kr) * C_CH] = bfb(va1[r]);
        }
        float vv = asum_acc;
        vv += __shfl_xor(vv, 1);
        vv += __shfl_xor(vv, 2);
        if (st4 == 0) aspart[blockIdx.x * K_CL + ks] = vv;
    } else {
        float* vb = vlad + (size_t)n * K_CL * C_CH;
        #pragma unroll
        for (int r = 0; r < 16; ++r) {
            const int kr = (r & 3) + 8 * (r >> 2) + 4 * h;
            atomicAdd(vb + (kr)      * C_CH + cB, va0[r]);
            atomicAdd(vb + (32 + kr) * C_CH + cB, va1[r]);
        }
        float vv = asum_acc;
        vv += __shfl_xor(vv, 1);
        vv += __shfl_xor(vv, 2);
        if (st4 == 0) atomicAdd(asum + n * K_CL + ks, vv);
    }
    #undef ISSUE_DMA
}

// store-path reducer
__global__ void k_rows_part(float* __restrict__ vlad, const unsigned short* __restrict__ part,
                            const float* __restrict__ aspart,
                            const float* __restrict__ cent)
{
    const int bx = blockIdx.x;            // n*64 + k
    const int n = bx >> 6, k = bx & 63;
    const int c = threadIdx.x;            // 128 threads
    const int b0 = n * BPI;
    float v = 0.f, a = 0.f;
    #pragma unroll
    for (int b = 0; b < BPI; ++b) {
        v += b2f(part[(size_t)(b0 + b) * (K_CL * C_CH) + k * C_CH + c]);
        a += aspart[(b0 + b) * K_CL + k];
    }
    v -= a * cent[k * C_CH + c];
    float ssq = v * v;
    #pragma unroll
    for (int m = 32; m >= 1; m >>= 1) ssq += __shfl_xor(ssq, m);
    __shared__ float sb[2];
    if ((threadIdx.x & 63) == 0) sb[threadIdx.x >> 6] = ssq;
    __syncthreads();
    float tot = sb[0] + sb[1];
    float sc = 1.f / fmaxf(sqrtf(tot), EPSF);
    vlad[((size_t)n * K_CL + k) * C_CH + c] = v * sc;
}

// atomic-path reducer (fallback)
__global__ void k_rows(float* __restrict__ vlad, const float* __restrict__ asum,
                       const float* __restrict__ cent)
{
    const int bx = blockIdx.x;
    const int n = bx >> 6, k = bx & 63;
    const int c = threadIdx.x;
    float a = asum[n * K_CL + k];
    size_t idx = ((size_t)n * K_CL + k) * C_CH + c;
    float v = vlad[idx] - a * cent[k * C_CH + c];
    float ssq = v * v;
    #pragma unroll
    for (int m = 32; m >= 1; m >>= 1) ssq += __shfl_xor(ssq, m);
    __shared__ float sb[2];
    if ((threadIdx.x & 63) == 0) sb[threadIdx.x >> 6] = ssq;
    __syncthreads();
    float tot = sb[0] + sb[1];
    float sc = 1.f / fmaxf(sqrtf(tot), EPSF);
    vlad[idx] = v * sc;
}

// projection: pw[j] cached in regs, 4 images per block; final norm fused
__global__ __launch_bounds__(256) void k_proj3(
    const float* __restrict__ vlad, const float* __restrict__ pw,
    const float* __restrict__ pbias, float* __restrict__ out)
{
    const int j  = blockIdx.x;
    const int n0 = blockIdx.y << 2;
    const int t  = threadIdx.x;
    const float4* wp = (const float4*)(pw + (size_t)j * (K_CL * C_CH));
    float4 wr[8];
    #pragma unroll
    for (int r = 0; r < 8; ++r) wr[r] = wp[t + 256 * r];
    __shared__ float sb[4], sb2[4];
    const float bias = pbias[j];
    #pragma unroll
    for (int u = 0; u < 4; ++u) {
        const int n = n0 + u;
        const float4* vp = (const float4*)(vlad + (size_t)n * (K_CL * C_CH));
        float s = 0.f, nn = 0.f;
        #pragma unroll
        for (int r = 0; r < 8; ++r) {
            float4 a = vp[t + 256 * r];
            s  += a.x * wr[r].x + a.y * wr[r].y + a.z * wr[r].z + a.w * wr[r].w;
            nn += a.x * a.x + a.y * a.y + a.z * a.z + a.w * a.w;
        }
        #pragma unroll
        for (int m = 32; m >= 1; m >>= 1) {
            s  += __shfl_xor(s, m);
            nn += __shfl_xor(nn, m);
        }
        if ((t & 63) == 0) { sb[t >> 6] = s; sb2[t >> 6] = nn; }
        __syncthreads();
        if (t == 0) {
            float tot = sb[0] + sb[1] + sb[2] + sb[3];
            float tss = sb2[0] + sb2[1] + sb2[2] + sb2[3];
            float inv = 1.f / fmaxf(sqrtf(tss), EPSF);
            out[n * C_CH + j] = tot * inv + bias;
        }
        __syncthreads();
    }
}

extern "C" void kernel_launch(void* const* d_in, const int* in_sizes, int n_in,
                              void* d_out, int out_size, void* d_ws, size_t ws_size,
                              hipStream_t stream)
{
    const float* x      = (const float*)d_in[0];
    const float* conv_w = (const float*)d_in[1];
    const float* cent   = (const float*)d_in[2];
    const float* pw     = (const float*)d_in[3];
    const float* pbias  = (const float*)d_in[4];
    float* out = (float*)d_out;
    float* ws  = (float*)d_ws;

    float* vlad            = ws + WS_VLAD;
    float* asum            = ws + WS_ASUM;
    unsigned short* part   = (unsigned short*)(ws + WS_PART);
    float* aspart          = ws + WS_ASP;

    const int use_part = (ws_size >= (size_t)WS_STORE_TOT * sizeof(float)) ? 1 : 0;

    if (!use_part) {
        hipLaunchKernelGGL(k_zero, dim3((WS_ZERO + 255) / 256), dim3(256), 0, stream,
                           ws, WS_ZERO);
    }
    hipLaunchKernelGGL(k_fused11, dim3(N_IMG * BPI), dim3(256), 0, stream,
                       x, conv_w, vlad, asum, part, aspart, use_part);
    if (use_part) {
        hipLaunchKernelGGL(k_rows_part, dim3(N_IMG * K_CL), dim3(C_CH), 0, stream,
                           vlad, part, aspart, cent);
    } else {
        hipLaunchKernelGGL(k_rows, dim3(N_IMG * K_CL), dim3(C_CH), 0, stream,
                           vlad, asum, cent);
    }
    hipLaunchKernelGGL(k_proj3, dim3(C_CH, N_IMG / 4), dim3(256), 0, stream,
                       vlad, pw, pbias, out);
}

// Round 15
// 57.490 us; speedup vs baseline: 1.0645x; 1.0645x over previous
//
#include <hip/hip_runtime.h>
#include <hip/hip_bf16.h>

typedef float f32x16 __attribute__((ext_vector_type(16)));
typedef short short8 __attribute__((ext_vector_type(8)));

#define N_IMG 32
#define C_CH  128
#define HW    9216
#define K_CL  64
#define EPSF  1e-12f

#define BPI   24      // blocks per image
#define PPB   384     // pixels per block
#define NIT   3       // iterations of 128 pixels

// ws layout (floats)
#define WS_VLAD 0
#define WS_ASUM (N_IMG*K_CL*C_CH)              // 262144
#define WS_ZERO (WS_ASUM + N_IMG*K_CL)         // 264192 (zeroed prefix, atomic path)
#define WS_PART WS_ZERO
#define NPART   (N_IMG*BPI)                    // 768
// part stored as bf16 (ushort): NPART*K_CL*C_CH shorts = half as many floats
#define WS_ASP  (WS_PART + NPART*K_CL*C_CH/2)  // + 3145728
#define WS_STORE_TOT (WS_ASP + NPART*K_CL)

__device__ __forceinline__ unsigned short bfb(float f) {
    __hip_bfloat16 h = __float2bfloat16(f);   // RNE
    return *reinterpret_cast<unsigned short*>(&h);
}
__device__ __forceinline__ float b2f(unsigned short s) {
    return __uint_as_float(((unsigned)s) << 16);
}

__global__ void k_zero(float* __restrict__ p, int cnt) {
    int i = blockIdx.x * blockDim.x + threadIdx.x;
    if (i < cnt) p[i] = 0.f;
}

__global__ __launch_bounds__(256, 3) void k_fused12(
    const float* __restrict__ x, const float* __restrict__ conv_w,
    float* __restrict__ vlad, float* __restrict__ asum,
    unsigned short* __restrict__ part, float* __restrict__ aspart, int use_part)
{
    // cw/s: pitch 256B, swizzle ^((row&7)<<4). x: pitch 128B, swizzle ^((row&7)<<4)
    __shared__ __align__(16) char cw_lds[64 * 256];    // conv_w bf16 [64k][128c]    16KB
    __shared__ __align__(16) char s_lds [64 * 256];    // e (unnorm) bf16 [64k][128p] 16KB
    __shared__ __align__(16) char x_lds [128 * 128];   // x*scn*inv bf16 [128c][64p]  16KB
    __shared__ __align__(16) float invt[128];          // per-pixel 1/sum             512B

    const int t  = threadIdx.x;
    const int w  = t >> 6;          // wave 0..3
    const int l  = t & 63;
    const int lp = l & 31;
    const int h  = l >> 5;
    const int n    = blockIdx.x / BPI;
    const int pblk = (blockIdx.x % BPI) * PPB;

    // ---- stage conv_w -> bf16, swizzled ----
    #pragma unroll
    for (int r = 0; r < 16; ++r) {
        int e  = t + 256 * r;          // bf16-pair index 0..4095
        int k  = e >> 6;
        int c2 = (e & 63) << 1;
        unsigned pa = (unsigned)bfb(conv_w[k * C_CH + c2]) |
                      ((unsigned)bfb(conv_w[k * C_CH + c2 + 1]) << 16);
        int addr = (((k << 8) | (c2 << 1)) ^ ((k & 7) << 4));
        *reinterpret_cast<unsigned*>(cw_lds + addr) = pa;
    }

    f32x16 va0, va1;
    #pragma unroll
    for (int r = 0; r < 16; ++r) { va0[r] = 0.f; va1[r] = 0.f; }
    float asum_acc = 0.f;           // strip accumulator (k = t>>2, strip = t&3)

    const int p  = w * 32 + lp;     // block-local pixel 0..127
    const int q  = p & 63;          // column within 64-pixel half
    const int myhalf = w >> 1;
    const int ks  = t >> 2;         // asum: my k row
    const int st4 = t & 3;          // asum: my 32-pixel strip
    const int hb  = h << 10;        // h-dependent row-offset component
    const float* xbase = x + (size_t)n * C_CH * HW;

    // ---- precomputed LDS address bases (few regs + compile-time imms) ----
    const int swzL = (lp & 7) << 4;
    const int hx   = h << 4;
    const int bA0  = (lp << 8)        | (hx ^ swzL);   // cw/s row lp    (+ s<<5 xor)
    const int bA1  = ((32 + lp) << 8) | (hx ^ swzL);   // cw/s row 32+lp
    const int cB   = 32 * w + lp;                       // my VLAD c-column
    const int swzC = (cB & 7) << 4;
    const int bXf  = (cB << 7) | (hx ^ swzC);          // x_lds read row cB
    int baseS[4];                                       // e-store bases (r&3)
    #pragma unroll
    for (int j = 0; j < 4; ++j)
        baseS[j] = (((p << 1) ^ ((j + 4 * h) << 4))) + hb;

    for (int it = 0; it < NIT; ++it) {
        const float* xp = xbase + pblk + it * 128 + p;

        // ---- deep-issue load window: ALL 64 loads issued before any use ----
        float xv[8][8];
        #pragma unroll
        for (int s = 0; s < 8; ++s)
            #pragma unroll
            for (int i = 0; i < 8; ++i)
                xv[s][i] = xp[(size_t)(16 * s + 8 * h + i) * HW];

        // ---- sumsq fp32, convert raw->bf16 (xv dies here) ----
        float ss = 0.f;
        short8 xb[8];
        #pragma unroll
        for (int s = 0; s < 8; ++s) {
            #pragma unroll
            for (int i = 0; i < 8; ++i) ss += xv[s][i] * xv[s][i];
            #pragma unroll
            for (int i = 0; i < 8; ++i) xb[s][i] = (short)bfb(xv[s][i]);
        }
        ss += __shfl_xor(ss, 32);
        const float scn = 1.f / fmaxf(sqrtf(ss), EPSF);   // per-pixel norm scale

        if (it == 0) __syncthreads();   // cw staging visible (first iter only)

        // ---- raw logits MFMA: [64k x 32p] per wave ----
        f32x16 d0, d1;
        #pragma unroll
        for (int r = 0; r < 16; ++r) { d0[r] = 0.f; d1[r] = 0.f; }
        #pragma unroll
        for (int s = 0; s < 8; ++s) {
            short8 a0 = *reinterpret_cast<const short8*>(cw_lds + (bA0 ^ (s << 5)));
            short8 a1 = *reinterpret_cast<const short8*>(cw_lds + (bA1 ^ (s << 5)));
            d0 = __builtin_amdgcn_mfma_f32_32x32x16_bf16(a0, xb[s], d0, 0, 0, 0);
            d1 = __builtin_amdgcn_mfma_f32_32x32x16_bf16(a1, xb[s], d1, 0, 0, 0);
        }
        // NOTE: no max-subtract. |logit·scn| <= ||w_k|| ~= 1.4 for these inputs,
        // so exp() is in [0.25, 4] — numerically safe without stabilization.

        __syncthreads();   // A: prev iter's s/x/invt readers done

        // ---- e = exp(d*scn) -> s_lds immediately; d dies here ----
        float sm = 0.f;
        #pragma unroll
        for (int r = 0; r < 16; ++r) {
            float e0 = __expf(d0[r] * scn); sm += e0;
            float e1 = __expf(d1[r] * scn); sm += e1;
            const int imm = ((r & 3) + 8 * (r >> 2)) << 8;   // compile-time
            *reinterpret_cast<short*>(s_lds + (baseS[r & 3] + imm))        = (short)bfb(e0);
            *reinterpret_cast<short*>(s_lds + (baseS[r & 3] + imm + 8192)) = (short)bfb(e1);
        }
        sm += __shfl_xor(sm, 32);
        const float inv = 1.f / sm;
        invt[p] = inv;                      // lanes l and l^32 write same value
        const float sc2 = scn * inv;        // fold BOTH scalars into x fragments

        // ---- half 0: waves 0,1 write x cols 0-63 (scaled at store) ----
        if (myhalf == 0) {
            #pragma unroll
            for (int j = 0; j < 8; ++j) {
                const int bx_ = (((q << 1) ^ (j << 4))) + hb;
                #pragma unroll
                for (int s = 0; s < 8; ++s)
                    *reinterpret_cast<short*>(x_lds + (bx_ + ((16 * s + j) << 7))) =
                        (short)bfb(b2f((unsigned short)xb[s][j]) * sc2);
            }
        }
        __syncthreads();   // B
        #pragma unroll
        for (int sp = 0; sp < 4; ++sp) {
            short8 bf = *reinterpret_cast<const short8*>(x_lds + (bXf ^ (sp << 5)));
            short8 s0 = *reinterpret_cast<const short8*>(s_lds + (bA0 ^ (sp << 5)));
            short8 s1 = *reinterpret_cast<const short8*>(s_lds + (bA1 ^ (sp << 5)));
            va0 = __builtin_amdgcn_mfma_f32_32x32x16_bf16(s0, bf, va0, 0, 0, 0);
            va1 = __builtin_amdgcn_mfma_f32_32x32x16_bf16(s1, bf, va1, 0, 0, 0);
        }
        __syncthreads();   // C

        // ---- half 1: waves 2,3 write x cols 64-127 ----
        if (myhalf == 1) {
            #pragma unroll
            for (int j = 0; j < 8; ++j) {
                const int bx_ = (((q << 1) ^ (j << 4))) + hb;
                #pragma unroll
                for (int s = 0; s < 8; ++s)
                    *reinterpret_cast<short*>(x_lds + (bx_ + ((16 * s + j) << 7))) =
                        (short)bfb(b2f((unsigned short)xb[s][j]) * sc2);
            }
        }
        __syncthreads();   // D
        #pragma unroll
        for (int sp = 0; sp < 4; ++sp) {
            short8 bf = *reinterpret_cast<const short8*>(x_lds + (bXf ^ (sp << 5)));
            short8 s0 = *reinterpret_cast<const short8*>(s_lds + ((bA0 ^ (sp << 5)) + 128));
            short8 s1 = *reinterpret_cast<const short8*>(s_lds + ((bA1 ^ (sp << 5)) + 128));
            va0 = __builtin_amdgcn_mfma_f32_32x32x16_bf16(s0, bf, va0, 0, 0, 0);
            va1 = __builtin_amdgcn_mfma_f32_32x32x16_bf16(s1, bf, va1, 0, 0, 0);
        }

        // ---- asum strips: k=t>>2, 32 pixels at strip t&3; soft = e*invt[p] ----
        {
            const int rowb = ks << 8;
            const int swz  = (ks & 7) << 4;
            const float* ivp = invt + st4 * 32;
            float a = 0.f;
            #pragma unroll
            for (int g = 0; g < 4; ++g) {
                int off = st4 * 64 + g * 16;
                short8 u = *reinterpret_cast<const short8*>(s_lds + ((rowb | off) ^ swz));
                float4 ia = *reinterpret_cast<const float4*>(ivp + g * 8);
                float4 ib = *reinterpret_cast<const float4*>(ivp + g * 8 + 4);
                a += b2f((unsigned short)u[0]) * ia.x + b2f((unsigned short)u[1]) * ia.y +
                     b2f((unsigned short)u[2]) * ia.z + b2f((unsigned short)u[3]) * ia.w;
                a += b2f((unsigned short)u[4]) * ib.x + b2f((unsigned short)u[5]) * ib.y +
                     b2f((unsigned short)u[6]) * ib.z + b2f((unsigned short)u[7]) * ib.w;
            }
            asum_acc += a;
        }
    }

    // ---- flush partials ----
    if (use_part) {
        unsigned short* pb_ = part + (size_t)blockIdx.x * (K_CL * C_CH) + cB;
        #pragma unroll
        for (int r = 0; r < 16; ++r) {
            const int kr = (r & 3) + 8 * (r >> 2) + 4 * h;
            pb_[(kr)      * C_CH] = bfb(va0[r]);
            pb_[(32 + kr) * C_CH] = bfb(va1[r]);
        }
        float v = asum_acc;
        v += __shfl_xor(v, 1);
        v += __shfl_xor(v, 2);
        if (st4 == 0) aspart[blockIdx.x * K_CL + ks] = v;
    } else {
        float* vb = vlad + (size_t)n * K_CL * C_CH;
        #pragma unroll
        for (int r = 0; r < 16; ++r) {
            const int kr = (r & 3) + 8 * (r >> 2) + 4 * h;
            atomicAdd(vb + (kr)      * C_CH + cB, va0[r]);
            atomicAdd(vb + (32 + kr) * C_CH + cB, va1[r]);
        }
        float v = asum_acc;
        v += __shfl_xor(v, 1);
        v += __shfl_xor(v, 2);
        if (st4 == 0) atomicAdd(asum + n * K_CL + ks, v);
    }
}

// store-path reducer: sum 24 bf16 block partials, subtract asum*centroid, intra-normalize
__global__ void k_rows_part(float* __restrict__ vlad, const unsigned short* __restrict__ part,
                            const float* __restrict__ aspart,
                            const float* __restrict__ cent)
{
    const int bx = blockIdx.x;            // n*64 + k
    const int n = bx >> 6, k = bx & 63;
    const int c = threadIdx.x;            // 128 threads
    const int b0 = n * BPI;
    float v = 0.f, a = 0.f;
    #pragma unroll
    for (int b = 0; b < BPI; ++b) {
        v += b2f(part[(size_t)(b0 + b) * (K_CL * C_CH) + k * C_CH + c]);
        a += aspart[(b0 + b) * K_CL + k];
    }
    v -= a * cent[k * C_CH + c];
    float ssq = v * v;
    #pragma unroll
    for (int m = 32; m >= 1; m >>= 1) ssq += __shfl_xor(ssq, m);
    __shared__ float sb[2];
    if ((threadIdx.x & 63) == 0) sb[threadIdx.x >> 6] = ssq;
    __syncthreads();
    float tot = sb[0] + sb[1];
    float sc = 1.f / fmaxf(sqrtf(tot), EPSF);
    vlad[((size_t)n * K_CL + k) * C_CH + c] = v * sc;
}

// atomic-path reducer (fallback)
__global__ void k_rows(float* __restrict__ vlad, const float* __restrict__ asum,
                       const float* __restrict__ cent)
{
    const int bx = blockIdx.x;
    const int n = bx >> 6, k = bx & 63;
    const int c = threadIdx.x;
    float a = asum[n * K_CL + k];
    size_t idx = ((size_t)n * K_CL + k) * C_CH + c;
    float v = vlad[idx] - a * cent[k * C_CH + c];
    float ssq = v * v;
    #pragma unroll
    for (int m = 32; m >= 1; m >>= 1) ssq += __shfl_xor(ssq, m);
    __shared__ float sb[2];
    if ((threadIdx.x & 63) == 0) sb[threadIdx.x >> 6] = ssq;
    __syncthreads();
    float tot = sb[0] + sb[1];
    float sc = 1.f / fmaxf(sqrtf(tot), EPSF);
    vlad[idx] = v * sc;
}

// projection: pw[j] cached in regs, 4 images per block; final norm fused
__global__ __launch_bounds__(256) void k_proj3(
    const float* __restrict__ vlad, const float* __restrict__ pw,
    const float* __restrict__ pbias, float* __restrict__ out)
{
    const int j  = blockIdx.x;        // 0..127
    const int n0 = blockIdx.y << 2;   // 0,4,...,28
    const int t  = threadIdx.x;
    const float4* wp = (const float4*)(pw + (size_t)j * (K_CL * C_CH));
    float4 wr[8];
    #pragma unroll
    for (int r = 0; r < 8; ++r) wr[r] = wp[t + 256 * r];
    __shared__ float sb[4], sb2[4];
    const float bias = pbias[j];
    #pragma unroll
    for (int u = 0; u < 4; ++u) {
        const int n = n0 + u;
        const float4* vp = (const float4*)(vlad + (size_t)n * (K_CL * C_CH));
        float s = 0.f, nn = 0.f;
        #pragma unroll
        for (int r = 0; r < 8; ++r) {
            float4 a = vp[t + 256 * r];
            s  += a.x * wr[r].x + a.y * wr[r].y + a.z * wr[r].z + a.w * wr[r].w;
            nn += a.x * a.x + a.y * a.y + a.z * a.z + a.w * a.w;
        }
        #pragma unroll
        for (int m = 32; m >= 1; m >>= 1) {
            s  += __shfl_xor(s, m);
            nn += __shfl_xor(nn, m);
        }
        if ((t & 63) == 0) { sb[t >> 6] = s; sb2[t >> 6] = nn; }
        __syncthreads();
        if (t == 0) {
            float tot = sb[0] + sb[1] + sb[2] + sb[3];
            float tss = sb2[0] + sb2[1] + sb2[2] + sb2[3];
            float inv = 1.f / fmaxf(sqrtf(tss), EPSF);
            out[n * C_CH + j] = tot * inv + bias;
        }
        __syncthreads();
    }
}

extern "C" void kernel_launch(void* const* d_in, const int* in_sizes, int n_in,
                              void* d_out, int out_size, void* d_ws, size_t ws_size,
                              hipStream_t stream)
{
    const float* x      = (const float*)d_in[0];
    const float* conv_w = (const float*)d_in[1];
    const float* cent   = (const float*)d_in[2];
    const float* pw     = (const float*)d_in[3];
    const float* pbias  = (const float*)d_in[4];
    float* out = (float*)d_out;
    float* ws  = (float*)d_ws;

    float* vlad            = ws + WS_VLAD;
    float* asum            = ws + WS_ASUM;
    unsigned short* part   = (unsigned short*)(ws + WS_PART);
    float* aspart          = ws + WS_ASP;

    const int use_part = (ws_size >= (size_t)WS_STORE_TOT * sizeof(float)) ? 1 : 0;

    if (!use_part) {
        hipLaunchKernelGGL(k_zero, dim3((WS_ZERO + 255) / 256), dim3(256), 0, stream,
                           ws, WS_ZERO);
    }
    hipLaunchKernelGGL(k_fused12, dim3(N_IMG * BPI), dim3(256), 0, stream,
                       x, conv_w, vlad, asum, part, aspart, use_part);
    if (use_part) {
        hipLaunchKernelGGL(k_rows_part, dim3(N_IMG * K_CL), dim3(C_CH), 0, stream,
                           vlad, part, aspart, cent);
    } else {
        hipLaunchKernelGGL(k_rows, dim3(N_IMG * K_CL), dim3(C_CH), 0, stream,
                           vlad, asum, cent);
    }
    hipLaunchKernelGGL(k_proj3, dim3(C_CH, N_IMG / 4), dim3(256), 0, stream,
                       vlad, pw, pbias, out);
}